// Round 1
// baseline (144.823 us; speedup 1.0000x reference)
//
#include <hip/hip_runtime.h>

// Fused 6-layer MLP: x[65536,784] -> tanh MLP -> outputs (out,h1..h5) concat in d_out.
// Block = 256 threads = 4 waves, handles 64 rows.
//   Phase 1: wave w computes layer-1 partial dot over k in [w*196, w*196+196),
//            lane = local row. x via per-lane float4 streams (L1-cached),
//            W1 via wave-uniform scalar loads (readfirstlane-forced SGPR index).
//   Phase 2: partials through padded LDS, 4 threads/row shfl-reduce, then
//            redundantly compute layers 2-6 from scalar-loaded tiny weights,
//            stores split 4-ways per row.

__global__ __launch_bounds__(256, 4)
void mlp_fused(const float* __restrict__ x,
               const float* __restrict__ W1, const float* __restrict__ b1,
               const float* __restrict__ W2, const float* __restrict__ b2,
               const float* __restrict__ W3, const float* __restrict__ b3,
               const float* __restrict__ W4, const float* __restrict__ b4,
               const float* __restrict__ W5, const float* __restrict__ b5,
               const float* __restrict__ W6, const float* __restrict__ b6,
               float* __restrict__ out)
{
    __shared__ float lds[64][4][13];   // [row][wave][j(pad 12->13)]

    const int tid  = threadIdx.x;
    const int wave = __builtin_amdgcn_readfirstlane(tid >> 6);  // force SGPR
    const int lane = tid & 63;
    const int row0 = blockIdx.x << 6;

    // ---------- layer 1 partials ----------
    float acc[12];
#pragma unroll
    for (int j = 0; j < 12; ++j) acc[j] = 0.f;

    const float4* xv4 = (const float4*)(x + (size_t)(row0 + lane) * 784 + wave * 196);
    const float*  w1p = W1 + wave * 196 * 12;   // wave-uniform base -> s_load

#pragma unroll 2
    for (int t = 0; t < 49; ++t) {
        float4 xv = xv4[t];
        const float* wk = w1p + t * 48;
#pragma unroll
        for (int j = 0; j < 12; ++j) {
            acc[j] += xv.x * wk[j];
            acc[j] += xv.y * wk[12 + j];
            acc[j] += xv.z * wk[24 + j];
            acc[j] += xv.w * wk[36 + j];
        }
    }

#pragma unroll
    for (int j = 0; j < 12; ++j) lds[lane][wave][j] = acc[j];
    __syncthreads();

    // ---------- epilogue: 4 threads per row ----------
    const int r   = tid >> 2;      // local row 0..63
    const int sub = tid & 3;       // k-partial index / store split
    const int row = row0 + r;

    float h1[12];
#pragma unroll
    for (int j = 0; j < 12; ++j) {
        float z = lds[r][sub][j];
        z += __shfl_xor(z, 1);
        z += __shfl_xor(z, 2);     // all 4 lanes now hold full sum
        h1[j] = tanhf(z + b1[j]);
    }

    float h2[10];
#pragma unroll
    for (int m = 0; m < 10; ++m) {
        float s = b2[m];
#pragma unroll
        for (int j = 0; j < 12; ++j) s += h1[j] * W2[j * 10 + m];
        h2[m] = tanhf(s);
    }

    float h3[8];
#pragma unroll
    for (int m = 0; m < 8; ++m) {
        float s = b3[m];
#pragma unroll
        for (int j = 0; j < 10; ++j) s += h2[j] * W3[j * 8 + m];
        h3[m] = tanhf(s);
    }

    float h4[6];
#pragma unroll
    for (int m = 0; m < 6; ++m) {
        float s = b4[m];
#pragma unroll
        for (int j = 0; j < 8; ++j) s += h3[j] * W4[j * 6 + m];
        h4[m] = tanhf(s);
    }

    float h5[4];
#pragma unroll
    for (int m = 0; m < 4; ++m) {
        float s = b5[m];
#pragma unroll
        for (int j = 0; j < 6; ++j) s += h4[j] * W5[j * 4 + m];
        h5[m] = tanhf(s);
    }

    float o[10];
#pragma unroll
    for (int m = 0; m < 10; ++m) {
        float s = b6[m];
#pragma unroll
        for (int j = 0; j < 4; ++j) s += h5[j] * W6[j * 10 + m];
        o[m] = s;   // logits: no tanh
    }

    // ---------- stores (split by sub across the 4 threads of each row) ----------
    const size_t H1 = 655360, H2 = 1441792, H3 = 2097152, H4 = 2621440, H5 = 3014656;

    for (int j = sub; j < 10; j += 4) out[(size_t)row * 10 + j]      = o[j];
    for (int j = sub; j < 12; j += 4) out[H1 + (size_t)row * 12 + j] = h1[j];
    for (int j = sub; j < 10; j += 4) out[H2 + (size_t)row * 10 + j] = h2[j];
    for (int j = sub; j < 8;  j += 4) out[H3 + (size_t)row * 8  + j] = h3[j];
    for (int j = sub; j < 6;  j += 4) out[H4 + (size_t)row * 6  + j] = h4[j];
    for (int j = sub; j < 4;  j += 4) out[H5 + (size_t)row * 4  + j] = h5[j];
}

extern "C" void kernel_launch(void* const* d_in, const int* in_sizes, int n_in,
                              void* d_out, int out_size, void* d_ws, size_t ws_size,
                              hipStream_t stream) {
    (void)in_sizes; (void)n_in; (void)d_ws; (void)ws_size; (void)out_size;
    mlp_fused<<<1024, 256, 0, stream>>>(
        (const float*)d_in[0],
        (const float*)d_in[1],  (const float*)d_in[2],
        (const float*)d_in[3],  (const float*)d_in[4],
        (const float*)d_in[5],  (const float*)d_in[6],
        (const float*)d_in[7],  (const float*)d_in[8],
        (const float*)d_in[9],  (const float*)d_in[10],
        (const float*)d_in[11], (const float*)d_in[12],
        (float*)d_out);
}

// Round 2
// 46.533 us; speedup vs baseline: 3.1123x; 3.1123x over previous
//
#include <hip/hip_runtime.h>

// Fused 6-layer MLP, v2: coalesced-line x reads + LDS-broadcast W1.
// Block = 256 threads = 64 rows x 4 k-sublanes. Grid = 1024 blocks.
//   lane = r*4 + sub: at iter i, subs 0..3 of row r read float4s covering
//   bytes [i*64, i*64+64) of the row -> every 64B line fetched once, fully
//   consumed in one instruction (FETCH = 1.0x).
//   W1 staged to LDS once/block; per iter each thread reads its 4 W1 rows
//   (12 x ds_read_b128, 16-lane broadcast + 2-way alias = free).
//   Reduce 4 partials via shfl_xor(1,2); tiny layers 2-6 redundant per lane;
//   vectorized stores (float2/float4) with compile-time reg indices.

__device__ __forceinline__ float ftanh(float v) {
    float e = __expf(2.0f * v);          // v_exp based; overflow -> inf -> 1.0
    return 1.0f - 2.0f / (e + 1.0f);
}

__global__ __launch_bounds__(256, 4)
void mlp_fused2(const float* __restrict__ x,
                const float* __restrict__ W1, const float* __restrict__ b1,
                const float* __restrict__ W2, const float* __restrict__ b2,
                const float* __restrict__ W3, const float* __restrict__ b3,
                const float* __restrict__ W4, const float* __restrict__ b4,
                const float* __restrict__ W5, const float* __restrict__ b5,
                const float* __restrict__ W6, const float* __restrict__ b6,
                float* __restrict__ out)
{
    __shared__ float4 ldsW1[2352];          // 784*12 floats = 37632 B

    const int tid = threadIdx.x;

    // ---- stage W1 into LDS (coalesced flat copy) ----
    const float4* w1v = (const float4*)W1;
    for (int t = tid; t < 2352; t += 256) ldsW1[t] = w1v[t];
    __syncthreads();

    const int lane = tid & 63;
    const int wave = tid >> 6;
    const int r    = lane >> 2;             // row within 16-row wave group
    const int sub  = lane & 3;              // k-quarter within 64B line
    const int row  = (blockIdx.x << 6) + (wave << 4) + r;

    // ---- layer 1: acc over k, 4 lanes per row ----
    float acc[12];
#pragma unroll
    for (int j = 0; j < 12; ++j) acc[j] = 0.f;

    const float4* xrow = (const float4*)(x + (size_t)row * 784);

    for (int i = 0; i < 49; ++i) {
        float4 xv = xrow[i * 4 + sub];                    // 64B line per row per iter
        const float4* wb = ldsW1 + i * 48 + sub * 12;     // 4 W1 rows = 12 float4
#pragma unroll
        for (int dk = 0; dk < 4; ++dk) {
            float xx = (dk == 0) ? xv.x : (dk == 1) ? xv.y : (dk == 2) ? xv.z : xv.w;
            float4 w0 = wb[dk * 3 + 0];
            float4 w1 = wb[dk * 3 + 1];
            float4 w2 = wb[dk * 3 + 2];
            acc[0] += xx * w0.x;  acc[1] += xx * w0.y;  acc[2]  += xx * w0.z;  acc[3]  += xx * w0.w;
            acc[4] += xx * w1.x;  acc[5] += xx * w1.y;  acc[6]  += xx * w1.z;  acc[7]  += xx * w1.w;
            acc[8] += xx * w2.x;  acc[9] += xx * w2.y;  acc[10] += xx * w2.z;  acc[11] += xx * w2.w;
        }
    }

    // ---- reduce 4 sub-partials (within 4-lane group) + bias + tanh ----
    float h1[12];
#pragma unroll
    for (int j = 0; j < 12; ++j) {
        float z = acc[j];
        z += __shfl_xor(z, 1);
        z += __shfl_xor(z, 2);
        h1[j] = ftanh(z + b1[j]);
    }

    // ---- tiny layers 2..6 (redundant on all 4 sub-lanes; uniform W via s_load) ----
    float h2[10];
#pragma unroll
    for (int m = 0; m < 10; ++m) {
        float s = b2[m];
#pragma unroll
        for (int j = 0; j < 12; ++j) s += h1[j] * W2[j * 10 + m];
        h2[m] = ftanh(s);
    }

    float h3[8];
#pragma unroll
    for (int m = 0; m < 8; ++m) {
        float s = b3[m];
#pragma unroll
        for (int j = 0; j < 10; ++j) s += h2[j] * W3[j * 8 + m];
        h3[m] = ftanh(s);
    }

    float h4[6];
#pragma unroll
    for (int m = 0; m < 6; ++m) {
        float s = b4[m];
#pragma unroll
        for (int j = 0; j < 8; ++j) s += h3[j] * W4[j * 6 + m];
        h4[m] = ftanh(s);
    }

    float h5[4];
#pragma unroll
    for (int m = 0; m < 4; ++m) {
        float s = b5[m];
#pragma unroll
        for (int j = 0; j < 6; ++j) s += h4[j] * W5[j * 4 + m];
        h5[m] = ftanh(s);
    }

    float o[10];
#pragma unroll
    for (int m = 0; m < 10; ++m) {
        float s = b6[m];
#pragma unroll
        for (int j = 0; j < 4; ++j) s += h5[j] * W6[j * 10 + m];
        o[m] = s;   // logits
    }

    // ---- vectorized stores, round-robined over sub (compile-time reg indices) ----
    const size_t H1 = 655360, H2 = 1441792, H3 = 2097152, H4 = 2621440, H5 = 3014656;
    float2* po  = (float2*)(out +      (size_t)row * 10);   // 8B aligned (row*40B)
    float4* ph1 = (float4*)(out + H1 + (size_t)row * 12);   // 16B aligned (row*48B)
    float2* ph2 = (float2*)(out + H2 + (size_t)row * 10);
    float4* ph3 = (float4*)(out + H3 + (size_t)row * 8);
    float2* ph4 = (float2*)(out + H4 + (size_t)row * 6);
    float4* ph5 = (float4*)(out + H5 + (size_t)row * 4);

    if (sub == 0) {
        po[0]  = make_float2(o[0], o[1]);
        po[4]  = make_float2(o[8], o[9]);
        ph2[0] = make_float2(h2[0], h2[1]);
        ph2[4] = make_float2(h2[8], h2[9]);
        ph4[1] = make_float2(h4[2], h4[3]);
    } else if (sub == 1) {
        po[1]  = make_float2(o[2], o[3]);
        ph1[0] = make_float4(h1[0], h1[1], h1[2], h1[3]);
        ph2[1] = make_float2(h2[2], h2[3]);
        ph3[0] = make_float4(h3[0], h3[1], h3[2], h3[3]);
        ph4[2] = make_float2(h4[4], h4[5]);
    } else if (sub == 2) {
        po[2]  = make_float2(o[4], o[5]);
        ph1[1] = make_float4(h1[4], h1[5], h1[6], h1[7]);
        ph2[2] = make_float2(h2[4], h2[5]);
        ph3[1] = make_float4(h3[4], h3[5], h3[6], h3[7]);
        ph5[0] = make_float4(h5[0], h5[1], h5[2], h5[3]);
    } else {
        po[3]  = make_float2(o[6], o[7]);
        ph1[2] = make_float4(h1[8], h1[9], h1[10], h1[11]);
        ph2[3] = make_float2(h2[6], h2[7]);
        ph4[0] = make_float2(h4[0], h4[1]);
    }
}

extern "C" void kernel_launch(void* const* d_in, const int* in_sizes, int n_in,
                              void* d_out, int out_size, void* d_ws, size_t ws_size,
                              hipStream_t stream) {
    (void)in_sizes; (void)n_in; (void)d_ws; (void)ws_size; (void)out_size;
    mlp_fused2<<<1024, 256, 0, stream>>>(
        (const float*)d_in[0],
        (const float*)d_in[1],  (const float*)d_in[2],
        (const float*)d_in[3],  (const float*)d_in[4],
        (const float*)d_in[5],  (const float*)d_in[6],
        (const float*)d_in[7],  (const float*)d_in[8],
        (const float*)d_in[9],  (const float*)d_in[10],
        (const float*)d_in[11], (const float*)d_in[12],
        (float*)d_out);
}